// Round 15
// baseline (32.194 us; speedup 1.0000x reference)
//
#include <hip/hip_runtime.h>
#include <hip/hip_bf16.h>

typedef unsigned short ushort_t;
typedef unsigned int uint_t;
typedef __attribute__((ext_vector_type(8))) short short8;
typedef __attribute__((ext_vector_type(4))) float f32x4;

#define IN_DIM 256
#define OUT_DIM 256
#define NSPL 11                  // 11 bases
#define KSLOT 12                 // + silu/residual slot
#define CHUNK_I 32               // inputs per K-chunk
#define KC (CHUNK_I * KSLOT)     // 384 K-slots per chunk
#define LSTRIDE (KC + 8)         // 392 ushorts = 784B row stride; slots KC..KC+7 = pad/dump
#define NCHUNK 8

__device__ __forceinline__ uint_t pk2(float lo, float hi) {
  __hip_bfloat162 h = __float22bfloat162_rn(make_float2(lo, hi));  // v_cvt_pk_bf16_f32, RNE
  union { __hip_bfloat162 h2; uint_t u; } c; c.h2 = h;
  return c.u;
}

// A-cell: closed-form cubic B-spline; placement via LDS scatter (address path).
// OOB slots (incl. J>10 cases hitting slots 11..13) redirect to the row pad.
__device__ __forceinline__ void packA_scatter(ushort_t* cb, ushort_t* dump, float xf) {
  const float t = (xf + 1.75f) * 4.0f;
  const float fJ = floorf(t);
  const int J = (int)fJ;
  const float u = t - fJ;
  const float u2 = u * u, u3 = u2 * u, um = 1.0f - u;
  const float n0 = um * um * um * (1.0f / 6.0f);                        // slot J-3
  const float n1 = 0.5f * u3 - u2 + (4.0f / 6.0f);                      // slot J-2
  const float n2 = -0.5f * u3 + 0.5f * u2 + 0.5f * u + (1.0f / 6.0f);   // slot J-1
  const float n3 = u3 * (1.0f / 6.0f);                                  // slot J
  const float silu = xf / (1.0f + __expf(-xf));

  // zero the 12-slot cell (24B, 8B-aligned; compiler merges to wide ds_writes)
#pragma unroll
  for (int z = 0; z < 12; ++z) cb[z] = 0;

  const uint_t p01 = pk2(n0, n1);
  const uint_t p23 = pk2(n2, n3);
  const uint_t psl = pk2(silu, silu);

  const int base = J - 3;
  ushort_t* w0 = ((unsigned)(base + 0) <= 10u) ? (cb + base + 0) : (dump + 0);
  ushort_t* w1 = ((unsigned)(base + 1) <= 10u) ? (cb + base + 1) : (dump + 1);
  ushort_t* w2 = ((unsigned)(base + 2) <= 10u) ? (cb + base + 2) : (dump + 2);
  ushort_t* w3 = ((unsigned)(base + 3) <= 10u) ? (cb + base + 3) : (dump + 3);
  *w0 = (ushort_t)p01;
  *w1 = (ushort_t)(p01 >> 16);
  *w2 = (ushort_t)p23;
  *w3 = (ushort_t)(p23 >> 16);
  cb[11] = (ushort_t)psl;
}

// ONE kernel, 512 blocks x 256 threads, zero cross-block sync, 3 blocks/CU.
// Per chunk: coalesced float2 coef loads + per-element uw broadcasts (prefetched
// 2 chunks ahead) -> direct bf16 scatter into the W tile at d = e + e/11
// (e/11 via exact magic mul, precomputed per thread). NO LDS transpose
// round-trip. A built via LDS scatter as before. One barrier per chunk.
__global__ __launch_bounds__(256, 3) void fused(const float* __restrict__ x,
                                                const float* __restrict__ coef,
                                                const float* __restrict__ rw,
                                                const float* __restrict__ uw,
                                                float* __restrict__ out) {
  __shared__ __attribute__((aligned(16))) ushort_t As[2][16 * LSTRIDE];
  __shared__ __attribute__((aligned(16))) ushort_t Ws[2][16 * LSTRIDE];
  __shared__ __attribute__((aligned(16))) f32x4 red[3][64];

  const int tid = threadIdx.x;
  const int lane = tid & 63;
  const int w = tid >> 6;                          // wave 0..3 = K-slice owner
  const int B = blockIdx.x;
  const int mt = B >> 4;                           // 0..31
  const int nt = ((B & 7) << 1) | ((B >> 3) & 1);  // XCD-aware: XCD r owns N-tiles {2r,2r+1}
  const int b0 = mt * 16, o0 = nt * 16;
  const int mn = lane & 15;
  const int klane = (lane >> 4) * 8;

  const int row = tid >> 4;                        // 0..15: tile row this thread builds
  const int i0 = tid & 15;                         // coef float2 column; cells (row,i0),(row,i0+16)

  const float* x_p  = x  + (size_t)(b0 + row) * IN_DIM;
  const int orow = o0 + row;
  const float* uw_p = uw + (size_t)orow * IN_DIM;
  const float* rw_p = rw + (size_t)orow * IN_DIM;
  const float* cf_p = coef + (size_t)orow * IN_DIM * NSPL;

  // chunk-invariant W-scatter geometry: element e -> cell q=e/11, dest slot e+q
  int q0[11], q1[11];
#pragma unroll
  for (int j = 0; j < 11; ++j) {
    const int e0 = 2 * i0 + 32 * j;
    q0[j] = (e0 * 5958) >> 16;          // exact floor(e/11) for e < 2366
    q1[j] = ((e0 + 1) * 5958) >> 16;
  }

  // two independent register stages (A=even chunks, B=odd)
  float2 cfA[11], cfB[11];
  float usA0[11], usA1[11], usB0[11], usB1[11];
  float xaA0, xaA1, rrA0, rrA1;
  float xaB0, xaB1, rrB0, rrB1;

#define LOADC(S, C)                                                           \
  {                                                                           \
    const int ib = (C) * CHUNK_I;                                             \
    xa##S##0 = x_p[ib + i0];                                                  \
    xa##S##1 = x_p[ib + i0 + 16];                                             \
    rr##S##0 = rw_p[ib + i0];                                                 \
    rr##S##1 = rw_p[ib + i0 + 16];                                            \
    const float2* csrc = (const float2*)(cf_p + (size_t)ib * NSPL);           \
    _Pragma("unroll")                                                         \
    for (int j = 0; j < 11; ++j) cf##S[j] = csrc[i0 + j * 16];                \
    _Pragma("unroll")                                                         \
    for (int j = 0; j < 11; ++j) {                                            \
      us##S##0[j] = uw_p[ib + q0[j]];                                         \
      us##S##1[j] = uw_p[ib + q1[j]];                                         \
    }                                                                         \
  }

#define CVTPACK(S, BUF)                                                       \
  {                                                                           \
    ushort_t* arow = &As[BUF][row * LSTRIDE];                                 \
    packA_scatter(arow + i0 * KSLOT, arow + KC, xa##S##0);                    \
    packA_scatter(arow + (i0 + 16) * KSLOT, arow + KC, xa##S##1);             \
    ushort_t* wrow = &Ws[BUF][row * LSTRIDE];                                 \
    _Pragma("unroll")                                                         \
    for (int j = 0; j < 11; ++j) {                                            \
      const int e0 = 2 * i0 + 32 * j;                                         \
      const uint_t pv = pk2(us##S##0[j] * cf##S[j].x,                         \
                            us##S##1[j] * cf##S[j].y);                        \
      wrow[e0 + q0[j]]     = (ushort_t)pv;                                    \
      wrow[e0 + 1 + q1[j]] = (ushort_t)(pv >> 16);                            \
    }                                                                         \
    wrow[i0 * KSLOT + 11]        = (ushort_t)pk2(rr##S##0, rr##S##0);         \
    wrow[(i0 + 16) * KSLOT + 11] = (ushort_t)pk2(rr##S##1, rr##S##1);         \
  }

#define MFMA3(BUF)                                                            \
  {                                                                           \
    _Pragma("unroll")                                                         \
    for (int q = 0; q < 3; ++q) {                                             \
      const int k = w * 96 + q * 32 + klane;                                  \
      short8 af  = *(const short8*)&As[BUF][mn * LSTRIDE + k];                \
      short8 bfr = *(const short8*)&Ws[BUF][mn * LSTRIDE + k];                \
      acc = __builtin_amdgcn_mfma_f32_16x16x32_bf16(af, bfr, acc, 0, 0, 0);   \
    }                                                                         \
  }

  f32x4 acc = {0.f, 0.f, 0.f, 0.f};

  // prologue: build chunk 0, put chunk 1 in flight
  LOADC(A, 0)
  CVTPACK(A, 0)
  LOADC(B, 1)
  __syncthreads();

#pragma unroll
  for (int cc = 0; cc < 4; ++cc) {
    // even chunk 2cc (buffer 0)
    MFMA3(0)
    if (cc < 3) { LOADC(A, 2 * cc + 2) }   // prefetch 2 ahead into freed A-stage
    CVTPACK(B, 1)                          // build odd chunk 2cc+1 (loaded a full phase ago)
    __syncthreads();

    // odd chunk 2cc+1 (buffer 1)
    MFMA3(1)
    if (cc < 3) {
      LOADC(B, 2 * cc + 3)                 // prefetch 2 ahead into freed B-stage
      CVTPACK(A, 0)                        // build even chunk 2cc+2
    }
    __syncthreads();
  }

  // cross-wave split-K reduce, then write
  if (w > 0) red[w - 1][lane] = acc;
  __syncthreads();

  if (w == 0) {
    const f32x4 t0 = red[0][lane];
    const f32x4 t1 = red[1][lane];
    const f32x4 t2 = red[2][lane];
#pragma unroll
    for (int q = 0; q < 4; ++q) acc[q] += t0[q] + t1[q] + t2[q];

    // C/D layout (HW-verified): col = lane&15, row = (lane>>4)*4 + reg
    const int col = o0 + mn;
    const int rbase = b0 + (lane >> 4) * 4;
#pragma unroll
    for (int r = 0; r < 4; ++r) {
      out[(size_t)(rbase + r) * OUT_DIM + col] = acc[r];
    }
  }
}

extern "C" void kernel_launch(void* const* d_in, const int* in_sizes, int n_in,
                              void* d_out, int out_size, void* d_ws, size_t ws_size,
                              hipStream_t stream) {
  const float* x    = (const float*)d_in[0];
  const float* coef = (const float*)d_in[1];
  const float* rw   = (const float*)d_in[2];
  const float* uw   = (const float*)d_in[3];
  float* out = (float*)d_out;

  fused<<<512, 256, 0, stream>>>(x, coef, rw, uw, out);
}

// Round 16
// 17.861 us; speedup vs baseline: 1.8024x; 1.8024x over previous
//
#include <hip/hip_runtime.h>
#include <hip/hip_bf16.h>

typedef unsigned short ushort_t;
typedef unsigned int uint_t;
typedef __attribute__((ext_vector_type(8))) short short8;
typedef __attribute__((ext_vector_type(4))) float f32x4;

#define IN_DIM 256
#define OUT_DIM 256
#define BATCH 512
#define NSPL 11
#define KSLOT 12
#define KDIM (IN_DIM * KSLOT)    // 3072
#define BKU 384                  // ushorts per row per chunk (32 inputs x 12)
#define NCHUNK 8

__device__ __forceinline__ uint_t pk2(float lo, float hi) {
  __hip_bfloat162 h = __float22bfloat162_rn(make_float2(lo, hi));  // v_cvt_pk_bf16_f32, RNE
  union { __hip_bfloat162 h2; uint_t u; } c; c.h2 = h;
  return c.u;
}

// ---- Kernel 1: build A[512][3072] and W[256][3072] (bf16, KSLOT-interleaved) ONCE ----
__global__ __launch_bounds__(256) void build_aw(const float* __restrict__ x,
                                                const float* __restrict__ coef,
                                                const float* __restrict__ rw,
                                                const float* __restrict__ uw,
                                                ushort_t* __restrict__ A,
                                                ushort_t* __restrict__ W) {
  __shared__ float rowc[IN_DIM * NSPL];            // 11.3 KB: one o-row of coef
  const int bx = blockIdx.x;
  const int t = threadIdx.x;

  if (bx < BATCH) {
    // A row b=bx, cell i=t: closed-form cubic B-spline + silu slot
    const float xf = x[bx * IN_DIM + t];
    const float tt = (xf + 1.75f) * 4.0f;
    const float fJ = floorf(tt);
    const int J = (int)fJ;
    const float u = tt - fJ;
    const float u2 = u * u, u3 = u2 * u, um = 1.0f - u;
    const float n0 = um * um * um * (1.0f / 6.0f);                        // slot J-3
    const float n1 = 0.5f * u3 - u2 + (4.0f / 6.0f);                      // slot J-2
    const float n2 = -0.5f * u3 + 0.5f * u2 + 0.5f * u + (1.0f / 6.0f);   // slot J-1
    const float n3 = u3 * (1.0f / 6.0f);                                  // slot J
    const float silu = xf / (1.0f + __expf(-xf));

    float v[12];
#pragma unroll
    for (int g = 0; g < NSPL; ++g) {
      float val = 0.0f;
      val = (J == g + 3) ? n0 : val;
      val = (J == g + 2) ? n1 : val;
      val = (J == g + 1) ? n2 : val;
      val = (J == g    ) ? n3 : val;
      v[g] = val;
    }
    v[11] = silu;

    uint_t* dst = (uint_t*)(A + (size_t)bx * KDIM + t * KSLOT);
#pragma unroll
    for (int j = 0; j < 6; ++j) dst[j] = pk2(v[2 * j], v[2 * j + 1]);
  } else {
    // W row o=bx-512: coalesced row-stage through LDS, then per-cell pack
    const int o = bx - BATCH;
    const float* src = coef + (size_t)o * IN_DIM * NSPL;     // 2816 floats
#pragma unroll
    for (int j = 0; j < 11; ++j) rowc[t + j * 256] = src[t + j * 256];
    __syncthreads();

    const float us = uw[o * IN_DIM + t];
    const float r  = rw[o * IN_DIM + t];
    const float* c = &rowc[t * NSPL];               // stride 11: bank-benign
    uint_t* dst = (uint_t*)(W + (size_t)o * KDIM + t * KSLOT);
    dst[0] = pk2(us * c[0], us * c[1]);
    dst[1] = pk2(us * c[2], us * c[3]);
    dst[2] = pk2(us * c[4], us * c[5]);
    dst[3] = pk2(us * c[6], us * c[7]);
    dst[4] = pk2(us * c[8], us * c[9]);
    dst[5] = pk2(us * c[10], r);
  }
}

// ---- Kernel 2: out = A · Wᵀ. 512 blocks x 4 waves; 16x16 tile; double-buffered
// LDS (linear 384-ushort rows + T2 XOR-swizzle), T14 issue-early/write-late
// reg staging, split-K across waves, one barrier per chunk. ----
__global__ __launch_bounds__(256, 3) void gemm(const ushort_t* __restrict__ A,
                                               const ushort_t* __restrict__ W,
                                               float* __restrict__ out) {
  __shared__ __attribute__((aligned(16))) ushort_t As[2][16 * BKU];   // 24.6 KB
  __shared__ __attribute__((aligned(16))) ushort_t Ws[2][16 * BKU];   // 24.6 KB
  __shared__ f32x4 red[3][64];

  const int tid = threadIdx.x;
  const int lane = tid & 63;
  const int w = tid >> 6;                          // wave 0..3 = K-slice owner
  const int B = blockIdx.x;
  const int mt = B >> 4;
  const int nt = ((B & 7) << 1) | ((B >> 3) & 1);  // XCD-aware (bijective, 512%8==0)
  const int b0 = mt * 16, o0 = nt * 16;
  const int mn = lane & 15;
  const int klane = (lane >> 4) * 8;

  // Staging geometry: wave w covers flat ushort range [(w*3+i)*512 .. +512), i=0..2,
  // 8 ushorts (16B) per lane. row = F/384, col = F%384 (chunk-invariant).
  int srcOff[3], ldsOff[3];
#pragma unroll
  for (int i = 0; i < 3; ++i) {
    const int F = ((w * 3 + i) * 64 + lane) * 8;
    const int rowi = F / BKU;                      // 0..15
    const int coli = F % BKU;
    srcOff[i] = rowi * KDIM + coli;                // global: linear, coalesced
    ldsOff[i] = rowi * BKU + (coli ^ ((rowi & 7) << 3));   // T2 swizzle (ushort units)
  }
  const ushort_t* Ap = A + (size_t)b0 * KDIM;
  const ushort_t* Wp = W + (size_t)o0 * KDIM;

  // MFMA read offsets (swizzled to match): lane reads row mn, k-slice of wave w
  const int mrow = mn * BKU;
  const int msw = (mn & 7) << 3;

  f32x4 acc = {0.f, 0.f, 0.f, 0.f};
  short8 sa0, sa1, sa2, sw0, sw1, sw2;

#define ISSUE(C)                                                              \
  {                                                                           \
    const int kb = (C) * BKU;                                                 \
    sa0 = *(const short8*)(Ap + srcOff[0] + kb);                              \
    sa1 = *(const short8*)(Ap + srcOff[1] + kb);                              \
    sa2 = *(const short8*)(Ap + srcOff[2] + kb);                              \
    sw0 = *(const short8*)(Wp + srcOff[0] + kb);                              \
    sw1 = *(const short8*)(Wp + srcOff[1] + kb);                              \
    sw2 = *(const short8*)(Wp + srcOff[2] + kb);                              \
  }

#define COMMIT(BUF)                                                           \
  {                                                                           \
    *(short8*)&As[BUF][ldsOff[0]] = sa0;                                      \
    *(short8*)&As[BUF][ldsOff[1]] = sa1;                                      \
    *(short8*)&As[BUF][ldsOff[2]] = sa2;                                      \
    *(short8*)&Ws[BUF][ldsOff[0]] = sw0;                                      \
    *(short8*)&Ws[BUF][ldsOff[1]] = sw1;                                      \
    *(short8*)&Ws[BUF][ldsOff[2]] = sw2;                                      \
  }

  // prologue: chunk 0 staged and committed
  ISSUE(0)
  COMMIT(0)
  __syncthreads();

  for (int c = 0; c < NCHUNK; ++c) {
    const int cur = c & 1;

    if (c + 1 < NCHUNK) { ISSUE(c + 1) }           // loads in flight during MFMA

    // MFMA: wave w owns K-slice [w*96, w*96+96) of this chunk
#pragma unroll
    for (int q = 0; q < 3; ++q) {
      const int kidx = w * 96 + q * 32 + klane;
      const int idx = mrow + (kidx ^ msw);
      short8 af  = *(const short8*)&As[cur][idx];
      short8 bfr = *(const short8*)&Ws[cur][idx];
      acc = __builtin_amdgcn_mfma_f32_16x16x32_bf16(af, bfr, acc, 0, 0, 0);
    }

    if (c + 1 < NCHUNK) { COMMIT(cur ^ 1) }        // write-late (waits vmcnt here)
    __syncthreads();
  }

  // cross-wave split-K reduce, then write
  if (w > 0) red[w - 1][lane] = acc;
  __syncthreads();

  if (w == 0) {
    const f32x4 t0 = red[0][lane];
    const f32x4 t1 = red[1][lane];
    const f32x4 t2 = red[2][lane];
#pragma unroll
    for (int q = 0; q < 4; ++q) acc[q] += t0[q] + t1[q] + t2[q];

    // C/D layout (HW-verified): col = lane&15, row = (lane>>4)*4 + reg
    const int col = o0 + mn;
    const int rbase = b0 + (lane >> 4) * 4;
#pragma unroll
    for (int r = 0; r < 4; ++r) {
      out[(size_t)(rbase + r) * OUT_DIM + col] = acc[r];
    }
  }
}

extern "C" void kernel_launch(void* const* d_in, const int* in_sizes, int n_in,
                              void* d_out, int out_size, void* d_ws, size_t ws_size,
                              hipStream_t stream) {
  const float* x    = (const float*)d_in[0];
  const float* coef = (const float*)d_in[1];
  const float* rw   = (const float*)d_in[2];
  const float* uw   = (const float*)d_in[3];
  float* out = (float*)d_out;

  ushort_t* A = (ushort_t*)d_ws;                             // 512*3072*2 = 3.0 MB
  ushort_t* W = A + (size_t)BATCH * KDIM;                    // 256*3072*2 = 1.5 MB

  build_aw<<<BATCH + OUT_DIM, 256, 0, stream>>>(x, coef, rw, uw, A, W);
  gemm<<<512, 256, 0, stream>>>(A, W, out);
}